// Round 1
// baseline (444.275 us; speedup 1.0000x reference)
//
#include <hip/hip_runtime.h>

// SparseMoE: B=2,S=2048 -> N=4096 tokens, D=1024, HIDDEN=2816, 8 experts, top-2, cap=1024
// ws usage ~268 MB (wb1/wb3/wb2 bf16, xb, h1, h3, o, router small buffers)

#define D_MODEL 1024
#define HIDDEN 2816
#define N_TOK 4096
#define CAP 1024

typedef __attribute__((ext_vector_type(8))) short short8;
typedef __attribute__((ext_vector_type(4))) float f32x4;

__device__ __forceinline__ unsigned short f2bf(float f) {
  unsigned int u = __float_as_uint(f);
  u += 0x7fffu + ((u >> 16) & 1u);   // RNE
  return (unsigned short)(u >> 16);
}
__device__ __forceinline__ float bf2f(unsigned short h) {
  return __uint_as_float(((unsigned int)h) << 16);
}

// ---------------- router: logits, noisy top-2, gates ----------------
__global__ void router_kernel(const float* __restrict__ x, const float* __restrict__ noise,
                              const float* __restrict__ rw, const float* __restrict__ rb,
                              const float* __restrict__ nw, const float* __restrict__ nb,
                              int* __restrict__ topi, float* __restrict__ gall,
                              int* __restrict__ slot) {
  int wid = threadIdx.x >> 6;
  int lane = threadIdx.x & 63;
  int t = blockIdx.x * 4 + wid;
  if (t >= N_TOK) return;
  const float* xr = x + (size_t)t * D_MODEL;
  double accL[8] = {0,0,0,0,0,0,0,0};
  double accN[8] = {0,0,0,0,0,0,0,0};
  for (int i = 0; i < 4; ++i) {
    int kb = (i * 64 + lane) * 4;
    float4 xv = *(const float4*)(xr + kb);
#pragma unroll
    for (int e = 0; e < 8; ++e) {
      float4 wv = *(const float4*)(rw + e * D_MODEL + kb);
      accL[e] += (double)xv.x * wv.x + (double)xv.y * wv.y + (double)xv.z * wv.z + (double)xv.w * wv.w;
      float4 nv = *(const float4*)(nw + e * D_MODEL + kb);
      accN[e] += (double)xv.x * nv.x + (double)xv.y * nv.y + (double)xv.z * nv.z + (double)xv.w * nv.w;
    }
  }
#pragma unroll
  for (int e = 0; e < 8; ++e) {
    for (int s = 32; s > 0; s >>= 1) {
      accL[e] += __shfl_xor(accL[e], s);
      accN[e] += __shfl_xor(accN[e], s);
    }
  }
  if (lane == 0) {
    double noisy[8];
#pragma unroll
    for (int e = 0; e < 8; ++e) {
      double lg = accL[e] + (double)rb[e];
      double nl = accN[e] + (double)nb[e];
      double sp = (nl > 0.0 ? nl : 0.0) + log1p(exp(-fabs(nl)));  // softplus, stable
      noisy[e] = lg + (double)noise[t * 8 + e] * sp;
    }
    int i0 = 0;
    for (int e = 1; e < 8; ++e) if (noisy[e] > noisy[i0]) i0 = e;   // ties -> lower idx
    int i1 = -1;
    for (int e = 0; e < 8; ++e) { if (e == i0) continue; if (i1 < 0 || noisy[e] > noisy[i1]) i1 = e; }
    double g0 = 1.0 / (1.0 + exp(noisy[i1] - noisy[i0]));
    topi[t * 2] = i0; topi[t * 2 + 1] = i1;
    gall[t * 2] = (float)g0; gall[t * 2 + 1] = (float)(1.0 - g0);
    slot[t * 2] = -1; slot[t * 2 + 1] = -1;
  }
}

// ---------------- per-expert capacity scan (token-index order) ----------------
__global__ void scan_kernel(const int* __restrict__ topi,
                            int* __restrict__ slot, int* __restrict__ tok_list) {
  int e = blockIdx.x;          // 8 blocks
  int tid = threadIdx.x;       // 1024 threads
  int lane = tid & 63, wid = tid >> 6;   // 16 waves
  __shared__ int wsum[16];
  __shared__ int base_s;
  tok_list[e * CAP + tid] = -1;
  if (tid == 0) base_s = 0;
  __syncthreads();
  for (int chunk = 0; chunk < N_TOK / 1024; ++chunk) {
    int t = chunk * 1024 + tid;
    int i0 = topi[t * 2], i1 = topi[t * 2 + 1];
    bool m = (i0 == e) || (i1 == e);
    unsigned long long mask = __ballot(m);
    int excl = __popcll(mask & ((1ull << lane) - 1ull));
    if (lane == 0) wsum[wid] = __popcll(mask);
    __syncthreads();
    int base = base_s;
    int woff = 0;
    for (int w = 0; w < wid; ++w) woff += wsum[w];
    int pos = base + woff + excl;
    if (m && pos < CAP) {
      tok_list[e * CAP + pos] = t;
      if (i0 == e) slot[t * 2] = pos; else slot[t * 2 + 1] = pos;
    }
    __syncthreads();
    if (tid == 0) {
      int s = 0;
      for (int w = 0; w < 16; ++w) s += wsum[w];
      base_s = base + s;
    }
    __syncthreads();
  }
}

// ---------------- gather x rows into per-expert bf16 buffers ----------------
__global__ void gather_kernel(const float* __restrict__ x, const int* __restrict__ tok_list,
                              unsigned short* __restrict__ xb) {
  int row = blockIdx.x;  // e*CAP + slot, 8192 blocks
  int tok = tok_list[row];
  unsigned short* dst = xb + (size_t)row * D_MODEL + threadIdx.x * 4;
  if (tok < 0) {
    *(ushort4*)dst = make_ushort4(0, 0, 0, 0);
  } else {
    float4 v = *(const float4*)(x + (size_t)tok * D_MODEL + threadIdx.x * 4);
    *(ushort4*)dst = make_ushort4(f2bf(v.x), f2bf(v.y), f2bf(v.z), f2bf(v.w));
  }
}

// ---------------- f32 -> bf16 weight convert ----------------
__global__ void cvt_kernel(const float* __restrict__ src, unsigned short* __restrict__ dst, int n4) {
  int i = blockIdx.x * blockDim.x + threadIdx.x;
  if (i >= n4) return;
  float4 v = *(const float4*)(src + (size_t)i * 4);
  *(ushort4*)(dst + (size_t)i * 4) = make_ushort4(f2bf(v.x), f2bf(v.y), f2bf(v.z), f2bf(v.w));
}

// ---------------- bf16 GEMM: C[M=CAP][N] = A[CAP][K] @ B[N][K]^T ----------------
// 128x128 tile, BK=64, 4 waves (2x2), mfma_f32_16x16x32_bf16, global_load_lds width 16.
template <bool CBF16, bool TWO>
__global__ __launch_bounds__(256)
void gemm_bt(const unsigned short* __restrict__ Ab, const unsigned short* __restrict__ B0,
             const unsigned short* __restrict__ B1, void* __restrict__ C0, void* __restrict__ C1,
             int N, int K) {
  int e, which;
  if (TWO) { e = blockIdx.z >> 1; which = blockIdx.z & 1; }
  else     { e = blockIdx.z; which = 0; }
  const unsigned short* A = Ab + (size_t)e * CAP * K;
  const unsigned short* B = ((TWO && which) ? B1 : B0) + (size_t)e * N * K;
  void* Cp = (TWO && which) ? C1 : C0;
  int bm = blockIdx.y, bn = blockIdx.x;
  __shared__ __align__(16) unsigned short As[128 * 64];
  __shared__ __align__(16) unsigned short Bs[128 * 64];
  int tid = threadIdx.x, lane = tid & 63, wid = tid >> 6;
  int wr = wid >> 1, wc = wid & 1;
  f32x4 acc[4][4] = {};
  for (int kt = 0; kt < K / 64; ++kt) {
#pragma unroll
    for (int i = 0; i < 4; ++i) {
      int c = wid * 4 + i;                    // 16 chunks of 1KB
      int r = 8 * c + (lane >> 3);
      int kof = (lane & 7) * 8;
      const unsigned short* ga = A + (size_t)(bm * 128 + r) * K + kt * 64 + kof;
      const unsigned short* gb = B + (size_t)(bn * 128 + r) * K + kt * 64 + kof;
      __builtin_amdgcn_global_load_lds((const __attribute__((address_space(1))) void*)ga,
                                       (__attribute__((address_space(3))) void*)(As + c * 512), 16, 0, 0);
      __builtin_amdgcn_global_load_lds((const __attribute__((address_space(1))) void*)gb,
                                       (__attribute__((address_space(3))) void*)(Bs + c * 512), 16, 0, 0);
    }
    __syncthreads();
#pragma unroll
    for (int kk = 0; kk < 2; ++kk) {
      short8 a[4], b[4];
#pragma unroll
      for (int mi = 0; mi < 4; ++mi) {
        int row = wr * 64 + mi * 16 + (lane & 15);
        a[mi] = *(const short8*)(As + row * 64 + kk * 32 + (lane >> 4) * 8);
      }
#pragma unroll
      for (int ni = 0; ni < 4; ++ni) {
        int row = wc * 64 + ni * 16 + (lane & 15);
        b[ni] = *(const short8*)(Bs + row * 64 + kk * 32 + (lane >> 4) * 8);
      }
#pragma unroll
      for (int mi = 0; mi < 4; ++mi)
#pragma unroll
        for (int ni = 0; ni < 4; ++ni)
          acc[mi][ni] = __builtin_amdgcn_mfma_f32_16x16x32_bf16(a[mi], b[ni], acc[mi][ni], 0, 0, 0);
    }
    __syncthreads();
  }
  size_t cb = (size_t)e * CAP * N;
#pragma unroll
  for (int mi = 0; mi < 4; ++mi) {
#pragma unroll
    for (int ni = 0; ni < 4; ++ni) {
      int col = bn * 128 + wc * 64 + ni * 16 + (lane & 15);
      int row0 = bm * 128 + wr * 64 + mi * 16 + (lane >> 4) * 4;
#pragma unroll
      for (int j = 0; j < 4; ++j) {
        size_t idx = cb + (size_t)(row0 + j) * N + col;
        if constexpr (CBF16) ((unsigned short*)Cp)[idx] = f2bf(acc[mi][ni][j]);
        else                 ((float*)Cp)[idx] = acc[mi][ni][j];
      }
    }
  }
}

// ---------------- h = silu(h1) * h3 (in place over h1) ----------------
__global__ void silu_kernel(unsigned short* __restrict__ h1, const unsigned short* __restrict__ h3,
                            int n4) {
  int i = blockIdx.x * blockDim.x + threadIdx.x;
  if (i >= n4) return;
  ushort4 a = *(const ushort4*)(h1 + (size_t)i * 4);
  ushort4 b = *(const ushort4*)(h3 + (size_t)i * 4);
  float av[4] = {bf2f(a.x), bf2f(a.y), bf2f(a.z), bf2f(a.w)};
  float bv[4] = {bf2f(b.x), bf2f(b.y), bf2f(b.z), bf2f(b.w)};
  unsigned short r[4];
#pragma unroll
  for (int j = 0; j < 4; ++j) {
    float s = av[j] / (1.0f + __expf(-av[j])) * bv[j];
    r[j] = f2bf(s);
  }
  *(ushort4*)(h1 + (size_t)i * 4) = make_ushort4(r[0], r[1], r[2], r[3]);
}

// ---------------- combine: out[t] = g0*o[e0][s0] + g1*o[e1][s1] ----------------
__global__ void combine_kernel(const float* __restrict__ o, const int* __restrict__ topi,
                               const float* __restrict__ gall, const int* __restrict__ slot,
                               float* __restrict__ out) {
  int t = blockIdx.x;
  int d = threadIdx.x * 4;
  int i0 = topi[t * 2], i1 = topi[t * 2 + 1];
  int s0 = slot[t * 2], s1 = slot[t * 2 + 1];
  float g0 = gall[t * 2], g1 = gall[t * 2 + 1];
  float4 r = make_float4(0.f, 0.f, 0.f, 0.f);
  if (s0 >= 0) {
    float4 v = *(const float4*)(o + ((size_t)i0 * CAP + s0) * D_MODEL + d);
    r.x += g0 * v.x; r.y += g0 * v.y; r.z += g0 * v.z; r.w += g0 * v.w;
  }
  if (s1 >= 0) {
    float4 v = *(const float4*)(o + ((size_t)i1 * CAP + s1) * D_MODEL + d);
    r.x += g1 * v.x; r.y += g1 * v.y; r.z += g1 * v.z; r.w += g1 * v.w;
  }
  *(float4*)(out + (size_t)t * D_MODEL + d) = r;
}

extern "C" void kernel_launch(void* const* d_in, const int* in_sizes, int n_in,
                              void* d_out, int out_size, void* d_ws, size_t ws_size,
                              hipStream_t stream) {
  const float* x     = (const float*)d_in[0];
  const float* noise = (const float*)d_in[1];
  const float* rw    = (const float*)d_in[2];
  const float* rb    = (const float*)d_in[3];
  const float* nw    = (const float*)d_in[4];
  const float* nb    = (const float*)d_in[5];
  const float* w1    = (const float*)d_in[6];
  const float* w3    = (const float*)d_in[7];
  const float* w2    = (const float*)d_in[8];
  float* out = (float*)d_out;

  char* ws = (char*)d_ws;
  size_t off = 0;
  auto alloc = [&](size_t bytes) -> void* {
    void* p = ws + off;
    off += (bytes + 255) & ~(size_t)255;
    return p;
  };
  const size_t WELEM = (size_t)8 * HIDDEN * D_MODEL;         // 23,068,672
  unsigned short* wb1 = (unsigned short*)alloc(WELEM * 2);
  unsigned short* wb3 = (unsigned short*)alloc(WELEM * 2);
  unsigned short* wb2 = (unsigned short*)alloc(WELEM * 2);
  unsigned short* xb  = (unsigned short*)alloc((size_t)8 * CAP * D_MODEL * 2);
  unsigned short* h1  = (unsigned short*)alloc((size_t)8 * CAP * HIDDEN * 2);
  unsigned short* h3  = (unsigned short*)alloc((size_t)8 * CAP * HIDDEN * 2);
  float*          ob  = (float*)alloc((size_t)8 * CAP * D_MODEL * 4);
  int*   topi = (int*)alloc(N_TOK * 2 * 4);
  float* gall = (float*)alloc(N_TOK * 2 * 4);
  int*   slot = (int*)alloc(N_TOK * 2 * 4);
  int*   tokl = (int*)alloc(8 * CAP * 4);
  (void)ws_size; (void)in_sizes; (void)n_in; (void)out_size;

  const int n4w = (int)(WELEM / 4);   // 5,767,168
  cvt_kernel<<<(n4w + 255) / 256, 256, 0, stream>>>(w1, wb1, n4w);
  cvt_kernel<<<(n4w + 255) / 256, 256, 0, stream>>>(w3, wb3, n4w);
  cvt_kernel<<<(n4w + 255) / 256, 256, 0, stream>>>(w2, wb2, n4w);

  router_kernel<<<N_TOK / 4, 256, 0, stream>>>(x, noise, rw, rb, nw, nb, topi, gall, slot);
  scan_kernel<<<8, 1024, 0, stream>>>(topi, slot, tokl);
  gather_kernel<<<8 * CAP, 256, 0, stream>>>(x, tokl, xb);

  dim3 g12(HIDDEN / 128, CAP / 128, 16);   // (22, 8, 16): z = e*2 + which
  gemm_bt<true, true><<<g12, 256, 0, stream>>>(xb, wb1, wb3, (void*)h1, (void*)h3, HIDDEN, D_MODEL);

  const int n4h = (int)((size_t)8 * CAP * HIDDEN / 4);  // 5,767,168
  silu_kernel<<<(n4h + 255) / 256, 256, 0, stream>>>(h1, h3, n4h);

  dim3 g3(D_MODEL / 128, CAP / 128, 8);    // (8, 8, 8)
  gemm_bt<false, false><<<g3, 256, 0, stream>>>(h1, wb2, nullptr, (void*)ob, nullptr, D_MODEL, HIDDEN);

  combine_kernel<<<N_TOK, 256, 0, stream>>>(ob, topi, gall, slot, out);
}

// Round 2
// 353.136 us; speedup vs baseline: 1.2581x; 1.2581x over previous
//
#include <hip/hip_runtime.h>

// SparseMoE: B=2,S=2048 -> N=4096 tokens, D=1024, HIDDEN=2816, 8 experts, top-2, cap=1024

#define D_MODEL 1024
#define HIDDEN 2816
#define N_TOK 4096
#define CAP 1024

typedef __attribute__((ext_vector_type(8))) short short8;
typedef __attribute__((ext_vector_type(4))) float f32x4;

__device__ __forceinline__ unsigned short f2bf(float f) {
  unsigned int u = __float_as_uint(f);
  u += 0x7fffu + ((u >> 16) & 1u);   // RNE
  return (unsigned short)(u >> 16);
}
__device__ __forceinline__ float bf2f(unsigned short h) {
  return __uint_as_float(((unsigned int)h) << 16);
}

template <int Ncnt> __device__ __forceinline__ void waitv() {
  if constexpr (Ncnt == 8)      asm volatile("s_waitcnt vmcnt(8)" ::: "memory");
  else if constexpr (Ncnt == 6) asm volatile("s_waitcnt vmcnt(6)" ::: "memory");
  else                          asm volatile("s_waitcnt vmcnt(0)" ::: "memory");
}

// ---------------- router: logits, noisy top-2, gates ----------------
__global__ void router_kernel(const float* __restrict__ x, const float* __restrict__ noise,
                              const float* __restrict__ rw, const float* __restrict__ rb,
                              const float* __restrict__ nw, const float* __restrict__ nb,
                              int* __restrict__ topi, float* __restrict__ gall,
                              int* __restrict__ slot) {
  int wid = threadIdx.x >> 6;
  int lane = threadIdx.x & 63;
  int t = blockIdx.x * 4 + wid;
  if (t >= N_TOK) return;
  const float* xr = x + (size_t)t * D_MODEL;
  double accL[8] = {0,0,0,0,0,0,0,0};
  double accN[8] = {0,0,0,0,0,0,0,0};
  for (int i = 0; i < 4; ++i) {
    int kb = (i * 64 + lane) * 4;
    float4 xv = *(const float4*)(xr + kb);
#pragma unroll
    for (int e = 0; e < 8; ++e) {
      float4 wv = *(const float4*)(rw + e * D_MODEL + kb);
      accL[e] += (double)xv.x * wv.x + (double)xv.y * wv.y + (double)xv.z * wv.z + (double)xv.w * wv.w;
      float4 nv = *(const float4*)(nw + e * D_MODEL + kb);
      accN[e] += (double)xv.x * nv.x + (double)xv.y * nv.y + (double)xv.z * nv.z + (double)xv.w * nv.w;
    }
  }
#pragma unroll
  for (int e = 0; e < 8; ++e) {
    for (int s = 32; s > 0; s >>= 1) {
      accL[e] += __shfl_xor(accL[e], s);
      accN[e] += __shfl_xor(accN[e], s);
    }
  }
  if (lane == 0) {
    double noisy[8];
#pragma unroll
    for (int e = 0; e < 8; ++e) {
      double lg = accL[e] + (double)rb[e];
      double nl = accN[e] + (double)nb[e];
      double sp = (nl > 0.0 ? nl : 0.0) + log1p(exp(-fabs(nl)));  // softplus, stable
      noisy[e] = lg + (double)noise[t * 8 + e] * sp;
    }
    int i0 = 0;
    for (int e = 1; e < 8; ++e) if (noisy[e] > noisy[i0]) i0 = e;
    int i1 = -1;
    for (int e = 0; e < 8; ++e) { if (e == i0) continue; if (i1 < 0 || noisy[e] > noisy[i1]) i1 = e; }
    double g0 = 1.0 / (1.0 + exp(noisy[i1] - noisy[i0]));
    topi[t * 2] = i0; topi[t * 2 + 1] = i1;
    gall[t * 2] = (float)g0; gall[t * 2 + 1] = (float)(1.0 - g0);
    slot[t * 2] = -1; slot[t * 2 + 1] = -1;
  }
}

// ---------------- per-expert capacity scan (token-index order) ----------------
__global__ void scan_kernel(const int* __restrict__ topi,
                            int* __restrict__ slot, int* __restrict__ tok_list) {
  int e = blockIdx.x;
  int tid = threadIdx.x;
  int lane = tid & 63, wid = tid >> 6;
  __shared__ int wsum[16];
  __shared__ int base_s;
  tok_list[e * CAP + tid] = -1;
  if (tid == 0) base_s = 0;
  __syncthreads();
  for (int chunk = 0; chunk < N_TOK / 1024; ++chunk) {
    int t = chunk * 1024 + tid;
    int i0 = topi[t * 2], i1 = topi[t * 2 + 1];
    bool m = (i0 == e) || (i1 == e);
    unsigned long long mask = __ballot(m);
    int excl = __popcll(mask & ((1ull << lane) - 1ull));
    if (lane == 0) wsum[wid] = __popcll(mask);
    __syncthreads();
    int base = base_s;
    int woff = 0;
    for (int w = 0; w < wid; ++w) woff += wsum[w];
    int pos = base + woff + excl;
    if (m && pos < CAP) {
      tok_list[e * CAP + pos] = t;
      if (i0 == e) slot[t * 2] = pos; else slot[t * 2 + 1] = pos;
    }
    __syncthreads();
    if (tid == 0) {
      int s = 0;
      for (int w = 0; w < 16; ++w) s += wsum[w];
      base_s = base + s;
    }
    __syncthreads();
  }
}

// ---------------- gather x rows into per-expert bf16 buffers ----------------
__global__ void gather_kernel(const float* __restrict__ x, const int* __restrict__ tok_list,
                              unsigned short* __restrict__ xb) {
  int row = blockIdx.x;
  int tok = tok_list[row];
  unsigned short* dst = xb + (size_t)row * D_MODEL + threadIdx.x * 4;
  if (tok < 0) {
    *(ushort4*)dst = make_ushort4(0, 0, 0, 0);
  } else {
    float4 v = *(const float4*)(x + (size_t)tok * D_MODEL + threadIdx.x * 4);
    *(ushort4*)dst = make_ushort4(f2bf(v.x), f2bf(v.y), f2bf(v.z), f2bf(v.w));
  }
}

// ---------------- f32 -> bf16 weight convert ----------------
__global__ void cvt_kernel(const float* __restrict__ src, unsigned short* __restrict__ dst, int n4) {
  int i = blockIdx.x * blockDim.x + threadIdx.x;
  if (i >= n4) return;
  float4 v = *(const float4*)(src + (size_t)i * 4);
  *(ushort4*)(dst + (size_t)i * 4) = make_ushort4(f2bf(v.x), f2bf(v.y), f2bf(v.z), f2bf(v.w));
}

// ============ pipelined 256-tile grouped GEMM: C[CAP][N] = A[CAP][K] @ B[N][K]^T ============
// BM=256, BN=256 or 128, BK=64, 8 waves (2M x 4N), T2 swizzle (src-side) + counted vmcnt +
// raw s_barrier + setprio. LDS: 2 x (A 32KB + B BN*128B).
template <int N, int K, int BN, bool CBF16, bool TWO>
__global__ __launch_bounds__(512, 2)
void gemm256(const unsigned short* __restrict__ Ab, const unsigned short* __restrict__ B0,
             const unsigned short* __restrict__ B1, void* __restrict__ C0, void* __restrict__ C1) {
  constexpr int NF = BN / 64;                 // n-fragments per wave
  constexpr int BUFSZ = 32768 + BN * 128;     // bytes per K-step buffer (A + B)
  constexpr int ACH = 32;                     // A chunks (256 rows / 8)
  constexpr int CH = ACH + BN / 8;            // total 1KB chunks per tile
  constexpr int CPW = CH / 8;                 // gload_lds per thread per stage (8 or 6)
  constexpr int KT = K / 64;
  constexpr int NBN = N / BN;
  constexpr int ZDIM = TWO ? 16 : 8;
  constexpr int PERZ = NBN * 4;
  constexpr int NWG = PERZ * ZDIM;

  __shared__ char smem[2 * BUFSZ];

  // ---- bijective XCD swizzle + decode ----
  int lid = blockIdx.x;
  int swz = (lid & 7) * (NWG / 8) + (lid >> 3);
  int z = swz / PERZ;
  int rem = swz - z * PERZ;
  int bm = rem / NBN;
  int bn = rem - bm * NBN;
  int e, which;
  if constexpr (TWO) { e = z >> 1; which = z & 1; } else { e = z; which = 0; }

  const unsigned short* A = Ab + (size_t)e * CAP * K;
  const unsigned short* B = ((TWO && which) ? B1 : B0) + (size_t)e * N * K;
  void* Cp = (TWO && which) ? C1 : C0;

  int tid = threadIdx.x, lane = tid & 63, wid = tid >> 6;
  int wr = wid >> 2, wc = wid & 3;            // 2 x 4 wave grid
  int lane15 = lane & 15, lhi = lane >> 4, l7 = lane & 7;

  // ---- stage source bases (pre-swizzled global address: slot ^= row&7) ----
  int lrow = lane >> 3;                       // 0..7 row within 8-row chunk
  int lcol = ((lane & 7) ^ lrow) * 8;         // permuted 16B slot -> short offset
  const unsigned short* Abase = A + (size_t)(bm * 256 + lrow) * K + lcol;
  const unsigned short* Bbase = B + (size_t)(bn * BN + lrow) * K + lcol;

  auto STAGE = [&](int ktile, int buf) {
    char* lb = smem + buf * BUFSZ;
#pragma unroll
    for (int i = 0; i < CPW; ++i) {
      int c = wid * CPW + i;
      if (c < ACH) {
        const unsigned short* g = Abase + (size_t)(c * 8) * K + ktile * 64;
        __builtin_amdgcn_global_load_lds((const __attribute__((address_space(1))) void*)g,
                                         (__attribute__((address_space(3))) void*)(lb + c * 1024), 16, 0, 0);
      } else {
        int cb = c - ACH;
        const unsigned short* g = Bbase + (size_t)(cb * 8) * K + ktile * 64;
        __builtin_amdgcn_global_load_lds((const __attribute__((address_space(1))) void*)g,
                                         (__attribute__((address_space(3))) void*)(lb + 32768 + cb * 1024), 16, 0, 0);
      }
    }
  };

  // ---- swizzled ds_read offsets (same involution as stage source) ----
  int sw0 = ((0 + lhi) ^ l7) * 16;            // kk=0 physical 16B slot
  int sw1 = ((4 + lhi) ^ l7) * 16;            // kk=1
  int aoff0 = wr * 16384 + lane15 * 128 + sw0;
  int aoff1 = wr * 16384 + lane15 * 128 + sw1;
  int boff0 = 32768 + (wc * (BN / 4) + lane15) * 128 + sw0;
  int boff1 = 32768 + (wc * (BN / 4) + lane15) * 128 + sw1;

  f32x4 acc[8][NF] = {};

  // ---- prologue: stage tiles 0,1 ----
  STAGE(0, 0);
  STAGE(1, 1);
  if constexpr (CPW == 8) waitv<8>(); else waitv<6>();
  __builtin_amdgcn_sched_barrier(0);
  __builtin_amdgcn_s_barrier();
  __builtin_amdgcn_sched_barrier(0);

  for (int kt = 0; kt < KT; ++kt) {
    char* cb = smem + (kt & 1) * BUFSZ;
    short8 a0[8], b0[NF], a1[8], b1[NF];
#pragma unroll
    for (int n = 0; n < NF; ++n) b0[n] = *(const short8*)(cb + boff0 + n * 2048);
#pragma unroll
    for (int m = 0; m < 8; ++m) a0[m] = *(const short8*)(cb + aoff0 + m * 2048);
    __builtin_amdgcn_s_setprio(1);
#pragma unroll
    for (int m = 0; m < 8; ++m)
#pragma unroll
      for (int n = 0; n < NF; ++n)
        acc[m][n] = __builtin_amdgcn_mfma_f32_16x16x32_bf16(a0[m], b0[n], acc[m][n], 0, 0, 0);
    __builtin_amdgcn_s_setprio(0);
#pragma unroll
    for (int n = 0; n < NF; ++n) b1[n] = *(const short8*)(cb + boff1 + n * 2048);
#pragma unroll
    for (int m = 0; m < 8; ++m) a1[m] = *(const short8*)(cb + aoff1 + m * 2048);
    // hazard gate: all ds_reads of this buffer issued -> safe to overwrite
    asm volatile("" ::: "memory");
    __builtin_amdgcn_sched_barrier(0);
    __builtin_amdgcn_s_barrier();
    __builtin_amdgcn_sched_barrier(0);
    if (kt + 2 < KT) STAGE(kt + 2, kt & 1);
    __builtin_amdgcn_s_setprio(1);
#pragma unroll
    for (int m = 0; m < 8; ++m)
#pragma unroll
      for (int n = 0; n < NF; ++n)
        acc[m][n] = __builtin_amdgcn_mfma_f32_16x16x32_bf16(a1[m], b1[n], acc[m][n], 0, 0, 0);
    __builtin_amdgcn_s_setprio(0);
    if (kt + 2 < KT) { if constexpr (CPW == 8) waitv<8>(); else waitv<6>(); }
    else if (kt + 1 < KT) waitv<0>();
    __builtin_amdgcn_sched_barrier(0);
    if (kt + 1 < KT) __builtin_amdgcn_s_barrier();
    __builtin_amdgcn_sched_barrier(0);
  }

  // ---- epilogue ----
  size_t cbase = (size_t)e * CAP * N;
#pragma unroll
  for (int m = 0; m < 8; ++m) {
#pragma unroll
    for (int n = 0; n < NF; ++n) {
      int row0 = bm * 256 + wr * 128 + m * 16 + lhi * 4;
      int col = bn * BN + wc * (BN / 4) + n * 16 + lane15;
#pragma unroll
      for (int j = 0; j < 4; ++j) {
        size_t idx = cbase + (size_t)(row0 + j) * N + col;
        if constexpr (CBF16) ((unsigned short*)Cp)[idx] = f2bf(acc[m][n][j]);
        else                 ((float*)Cp)[idx] = acc[m][n][j];
      }
    }
  }
}

// ---------------- h = silu(h1) * h3 (in place over h1) ----------------
__global__ void silu_kernel(unsigned short* __restrict__ h1, const unsigned short* __restrict__ h3,
                            int n4) {
  int i = blockIdx.x * blockDim.x + threadIdx.x;
  if (i >= n4) return;
  ushort4 a = *(const ushort4*)(h1 + (size_t)i * 4);
  ushort4 b = *(const ushort4*)(h3 + (size_t)i * 4);
  float av[4] = {bf2f(a.x), bf2f(a.y), bf2f(a.z), bf2f(a.w)};
  float bv[4] = {bf2f(b.x), bf2f(b.y), bf2f(b.z), bf2f(b.w)};
  unsigned short r[4];
#pragma unroll
  for (int j = 0; j < 4; ++j) {
    float s = av[j] / (1.0f + __expf(-av[j])) * bv[j];
    r[j] = f2bf(s);
  }
  *(ushort4*)(h1 + (size_t)i * 4) = make_ushort4(r[0], r[1], r[2], r[3]);
}

// ---------------- combine ----------------
__global__ void combine_kernel(const float* __restrict__ o, const int* __restrict__ topi,
                               const float* __restrict__ gall, const int* __restrict__ slot,
                               float* __restrict__ out) {
  int t = blockIdx.x;
  int d = threadIdx.x * 4;
  int i0 = topi[t * 2], i1 = topi[t * 2 + 1];
  int s0 = slot[t * 2], s1 = slot[t * 2 + 1];
  float g0 = gall[t * 2], g1 = gall[t * 2 + 1];
  float4 r = make_float4(0.f, 0.f, 0.f, 0.f);
  if (s0 >= 0) {
    float4 v = *(const float4*)(o + ((size_t)i0 * CAP + s0) * D_MODEL + d);
    r.x += g0 * v.x; r.y += g0 * v.y; r.z += g0 * v.z; r.w += g0 * v.w;
  }
  if (s1 >= 0) {
    float4 v = *(const float4*)(o + ((size_t)i1 * CAP + s1) * D_MODEL + d);
    r.x += g1 * v.x; r.y += g1 * v.y; r.z += g1 * v.z; r.w += g1 * v.w;
  }
  *(float4*)(out + (size_t)t * D_MODEL + d) = r;
}

extern "C" void kernel_launch(void* const* d_in, const int* in_sizes, int n_in,
                              void* d_out, int out_size, void* d_ws, size_t ws_size,
                              hipStream_t stream) {
  const float* x     = (const float*)d_in[0];
  const float* noise = (const float*)d_in[1];
  const float* rw    = (const float*)d_in[2];
  const float* rb    = (const float*)d_in[3];
  const float* nw    = (const float*)d_in[4];
  const float* nb    = (const float*)d_in[5];
  const float* w1    = (const float*)d_in[6];
  const float* w3    = (const float*)d_in[7];
  const float* w2    = (const float*)d_in[8];
  float* out = (float*)d_out;

  char* ws = (char*)d_ws;
  size_t off = 0;
  auto alloc = [&](size_t bytes) -> void* {
    void* p = ws + off;
    off += (bytes + 255) & ~(size_t)255;
    return p;
  };
  const size_t WELEM = (size_t)8 * HIDDEN * D_MODEL;
  unsigned short* wb1 = (unsigned short*)alloc(WELEM * 2);
  unsigned short* wb3 = (unsigned short*)alloc(WELEM * 2);
  unsigned short* wb2 = (unsigned short*)alloc(WELEM * 2);
  unsigned short* xb  = (unsigned short*)alloc((size_t)8 * CAP * D_MODEL * 2);
  unsigned short* h1  = (unsigned short*)alloc((size_t)8 * CAP * HIDDEN * 2);
  unsigned short* h3  = (unsigned short*)alloc((size_t)8 * CAP * HIDDEN * 2);
  float*          ob  = (float*)alloc((size_t)8 * CAP * D_MODEL * 4);
  int*   topi = (int*)alloc(N_TOK * 2 * 4);
  float* gall = (float*)alloc(N_TOK * 2 * 4);
  int*   slot = (int*)alloc(N_TOK * 2 * 4);
  int*   tokl = (int*)alloc(8 * CAP * 4);
  (void)ws_size; (void)in_sizes; (void)n_in; (void)out_size;

  const int n4w = (int)(WELEM / 4);
  cvt_kernel<<<(n4w + 255) / 256, 256, 0, stream>>>(w1, wb1, n4w);
  cvt_kernel<<<(n4w + 255) / 256, 256, 0, stream>>>(w3, wb3, n4w);
  cvt_kernel<<<(n4w + 255) / 256, 256, 0, stream>>>(w2, wb2, n4w);

  router_kernel<<<N_TOK / 4, 256, 0, stream>>>(x, noise, rw, rb, nw, nb, topi, gall, slot);
  scan_kernel<<<8, 1024, 0, stream>>>(topi, slot, tokl);
  gather_kernel<<<8 * CAP, 256, 0, stream>>>(x, tokl, xb);

  // GEMM12: per (expert, which) z-slice, N=2816, K=1024, BN=256 -> 11*4*16 = 704 wgs
  gemm256<HIDDEN, D_MODEL, 256, true, true><<<dim3(704), 512, 0, stream>>>(
      xb, wb1, wb3, (void*)h1, (void*)h3);

  const int n4h = (int)((size_t)8 * CAP * HIDDEN / 4);
  silu_kernel<<<(n4h + 255) / 256, 256, 0, stream>>>(h1, h3, n4h);

  // GEMM3: N=1024, K=2816, BN=128 -> 8*4*8 = 256 wgs (exactly 1 per CU)
  gemm256<D_MODEL, HIDDEN, 128, false, false><<<dim3(256), 512, 0, stream>>>(
      h1, wb2, nullptr, (void*)ob, nullptr);

  combine_kernel<<<N_TOK, 256, 0, stream>>>(ob, topi, gall, slot, out);
}